// Round 2
// baseline (294.363 us; speedup 1.0000x reference)
//
#include <hip/hip_runtime.h>
#include <cstdint>
#include <cstddef>

#define BB 8
#define NN 48
#define DD 33
#define XS 40            // xw/sw/ct row stride in floats (16B-aligned, zero-padded)
#define KP 128           // merged-K: [0,40)=xi*xj, [40,80)=xi*s, [80,120)=xj*s, 120=const
#define HH 32
#define MM (NN*NN)       // 2304 rows (i,j)
#define NC (NN*HH)       // 1536 cols (k,h)
#define TILE 96
#define TM (MM/TILE)     // 24 M-tiles
#define TN (NC/TILE)     // 16 N-tiles
#define NBLK (TM*TN*BB)  // 3072 gemm blocks (ticket target)
#define LDK 136          // LDS row stride f16 (+8 pad)

typedef __attribute__((ext_vector_type(8))) _Float16 f16x8;
typedef __attribute__((ext_vector_type(4))) float f32x4;

// ---- Kernel A: gather xw (padded), s = mean_i x, transpose coefs -> ct,
// ----           zero global h-accumulator + ticket counter -----------------------
__global__ void k_setup(const int* __restrict__ xcat, const float* __restrict__ xfeat,
                        const float* __restrict__ embed, const float* __restrict__ coefs,
                        float* __restrict__ xw, float* __restrict__ sw,
                        float* __restrict__ ct, float* __restrict__ hacc_g,
                        unsigned int* __restrict__ counter) {
    int b = blockIdx.x, t = threadIdx.x;
    if (b < BB) {
        for (int idx = t; idx < NN * XS; idx += 256) {
            int i = idx / XS, d = idx - i * XS;
            float v = 0.f;
            if (d < 32)       v = embed[xcat[b * NN + i] * 32 + d];
            else if (d == 32) v = xfeat[b * NN + i];
            xw[b * NN * XS + idx] = v;
        }
        __syncthreads();
        if (t < XS) {
            float a = 0.f;
            for (int i = 0; i < NN; ++i) a += xw[b * NN * XS + i * XS + t];
            sw[b * XS + t] = a * (1.0f / 48.0f);
        }
    } else if (b == BB) {
        // ct[(q*32+h)*40 + d] = coefs[(d*8+q)*32 + h], zero-padded d>=33
        for (int idx = t; idx < 8 * HH * XS; idx += 256) {
            int qh = idx / XS, d = idx - qh * XS;
            int q = qh >> 5, h = qh & 31;
            ct[idx] = (d < DD) ? coefs[(d * 8 + q) * HH + h] : 0.f;
        }
    } else {
        // re-poison safe: zero accumulators every launch/replay
        if (t < BB * HH) hacc_g[t] = 0.f;
        if (t == 0) *counter = 0u;
    }
}

// ---- Kernel B: fused build(A,B) + 96x96 MFMA tile per block (3072 blocks);
// ----           relu + h-sum in regs -> global atomics -> last-block finalize ----
__global__ __launch_bounds__(256, 3) void k_gemm(
        const float* __restrict__ xw, const float* __restrict__ sw,
        const float* __restrict__ ct, const float* __restrict__ eq_bias,
        float* __restrict__ hacc_g, unsigned int* __restrict__ counter,
        const float* __restrict__ out_w, const float* __restrict__ out_b,
        float* __restrict__ out) {
    __shared__ __align__(16) _Float16 As[TILE][LDK];
    __shared__ __align__(16) _Float16 Bs[TILE][LDK];
    __shared__ float gbuf[TILE];
    __shared__ float hacc[HH];
    __shared__ int lastFlag;

    int t = threadIdx.x;
    int bx = blockIdx.x, by = blockIdx.y, b = blockIdx.z;
    int N0 = bx * TILE, M0 = by * TILE;
    const float* xb = xw + b * NN * XS;
    const float* sb = sw + b * XS;

    if (t < HH) hacc[t] = 0.f;
    // const-K column values g[n] = sum_d s^2 (c4*x_k + c7*s) + bias_h, n = (k,h)
    if (t < TILE) {
        int n = N0 + t, k = n >> 5, h = n & 31;
        const float* xk = xb + k * XS;
        const float* c4 = ct + (4 * HH + h) * XS;
        const float* c7 = ct + (7 * HH + h) * XS;
        float g = 0.f;
        for (int d = 0; d < DD; ++d) {
            float sd = sb[d];
            g += sd * sd * (c4[d] * xk[d] + c7[d] * sd);
        }
        gbuf[t] = g + eq_bias[h];
    }
    __syncthreads();

    // ---- build B tile (rows = (k,h)) and A tile (rows = (i,j)); no sync between ----
    for (int c = 0; c < 6; ++c) {
        int ch = c * 256 + t;
        int row = ch >> 4, d0 = (ch & 15) * 8;
        // B row
        {
            int n = N0 + row, k = n >> 5, h = n & 31;
            const float* xk = xb + k * XS;
            f16x8 v;
            if (d0 < 120) {
                int seg = (d0 >= 80) ? 2 : (d0 >= 40) ? 1 : 0;
                int d = d0 - seg * 40;
                const int QA[3] = {0, 2, 1}, QB[3] = {3, 6, 5};
                const float* ca = ct + (QA[seg] * HH + h) * XS + d;
                const float* cb = ct + (QB[seg] * HH + h) * XS + d;
                f32x4 ca0 = *(const f32x4*)(ca),     ca1 = *(const f32x4*)(ca + 4);
                f32x4 cb0 = *(const f32x4*)(cb),     cb1 = *(const f32x4*)(cb + 4);
                f32x4 xk0 = *(const f32x4*)(xk + d), xk1 = *(const f32x4*)(xk + d + 4);
                f32x4 sb0 = *(const f32x4*)(sb + d), sb1 = *(const f32x4*)(sb + d + 4);
                f32x4 r0 = ca0 * xk0 + cb0 * sb0;
                f32x4 r1 = ca1 * xk1 + cb1 * sb1;
                for (int e = 0; e < 4; ++e) { v[e] = (_Float16)r0[e]; v[4 + e] = (_Float16)r1[e]; }
            } else {
                v = (f16x8){0, 0, 0, 0, 0, 0, 0, 0};
                v[0] = (_Float16)gbuf[row];
            }
            *(f16x8*)&Bs[row][d0] = v;
        }
        // A row
        {
            int grow = M0 + row;
            int i = grow / NN, j = grow - i * NN;
            f16x8 v;
            if (d0 < 120) {
                int seg = (d0 >= 80) ? 2 : (d0 >= 40) ? 1 : 0;
                int d = d0 - seg * 40;
                const float* p1 = (seg == 2) ? (xb + j * XS) : (xb + i * XS);
                const float* p2 = (seg == 0) ? (xb + j * XS) : sb;
                f32x4 a0 = *(const f32x4*)(p1 + d), a1 = *(const f32x4*)(p1 + d + 4);
                f32x4 b0 = *(const f32x4*)(p2 + d), b1 = *(const f32x4*)(p2 + d + 4);
                f32x4 r0 = a0 * b0, r1 = a1 * b1;
                for (int e = 0; e < 4; ++e) { v[e] = (_Float16)r0[e]; v[4 + e] = (_Float16)r1[e]; }
            } else {
                v = (f16x8){0, 0, 0, 0, 0, 0, 0, 0};
                v[0] = (_Float16)1.f;
            }
            *(f16x8*)&As[row][d0] = v;
        }
    }
    __syncthreads();

    int lane = t & 63, wave = t >> 6;
    int wm = (wave >> 1) * 48, wn = (wave & 1) * 48;
    int lrow = lane & 15, quad = lane >> 4;

    f32x4 acc[3][3];
#pragma unroll
    for (int m3 = 0; m3 < 3; ++m3)
#pragma unroll
        for (int nt = 0; nt < 3; ++nt)
            acc[m3][nt] = (f32x4){0.f, 0.f, 0.f, 0.f};

#pragma unroll
    for (int ks = 0; ks < 4; ++ks) {
        f16x8 af[3], bf[3];
#pragma unroll
        for (int m3 = 0; m3 < 3; ++m3)
            af[m3] = *(const f16x8*)&As[wm + m3 * 16 + lrow][ks * 32 + quad * 8];
#pragma unroll
        for (int nt = 0; nt < 3; ++nt)
            bf[nt] = *(const f16x8*)&Bs[wn + nt * 16 + lrow][ks * 32 + quad * 8];
#pragma unroll
        for (int m3 = 0; m3 < 3; ++m3)
#pragma unroll
            for (int nt = 0; nt < 3; ++nt)
                acc[m3][nt] = __builtin_amdgcn_mfma_f32_16x16x32_f16(af[m3], bf[nt], acc[m3][nt], 0, 0, 0);
    }

    // ---- relu + reduce: quads -> LDS -> global atomics ----
    float fs[3] = {0.f, 0.f, 0.f};
#pragma unroll
    for (int m3 = 0; m3 < 3; ++m3)
#pragma unroll
        for (int nt = 0; nt < 3; ++nt)
#pragma unroll
            for (int r = 0; r < 4; ++r)
                fs[nt] += fmaxf(acc[m3][nt][r], 0.f);

#pragma unroll
    for (int nt = 0; nt < 3; ++nt) {
        float v = fs[nt];
        v += __shfl_xor(v, 16);
        v += __shfl_xor(v, 32);
        if (lane < 16) atomicAdd(&hacc[(wn + nt * 16 + lane) & 31], v);
    }
    __syncthreads();
    if (t < HH) atomicAdd(&hacc_g[b * HH + t], hacc[t]);
    __threadfence();
    __syncthreads();
    if (t == 0) {
        unsigned int tk = atomicAdd(counter, 1u);
        lastFlag = (tk == NBLK - 1) ? 1 : 0;
    }
    __syncthreads();

    // ---- last block finalizes all 8 batches: relu(mean) @ out_w + out_b ----
    if (lastFlag) {
        int bb = t >> 5, h2 = t & 31;
        float v = atomicAdd(&hacc_g[bb * HH + h2], 0.f);   // coherent read via RMW
        float m = v * (1.0f / 110592.0f);
        float r = fmaxf(m, 0.f) * out_w[h2];
        r += __shfl_xor(r, 1);
        r += __shfl_xor(r, 2);
        r += __shfl_xor(r, 4);
        r += __shfl_xor(r, 8);
        r += __shfl_xor(r, 16);
        if (h2 == 0) out[bb] = r + out_b[0];
    }
}

extern "C" void kernel_launch(void* const* d_in, const int* in_sizes, int n_in,
                              void* d_out, int out_size, void* d_ws, size_t ws_size,
                              hipStream_t stream) {
    (void)in_sizes; (void)n_in; (void)out_size; (void)ws_size;
    const int*   xcat    = (const int*)d_in[0];
    const float* xfeat   = (const float*)d_in[1];
    const float* embed   = (const float*)d_in[2];
    const float* coefs   = (const float*)d_in[3];
    const float* eq_bias = (const float*)d_in[4];
    const float* out_w   = (const float*)d_in[5];
    const float* out_b   = (const float*)d_in[6];
    float* out = (float*)d_out;

    // Workspace layout (16B-aligned), total ~105 KB
    char* w = (char*)d_ws;
    float*        xw      = (float*)(w + 0);        // 8*48*40 f32 = 61440 B
    float*        sw      = (float*)(w + 61440);    // 8*40 f32    = 1280 B
    float*        ct      = (float*)(w + 62720);    // 8*32*40 f32 = 40960 B
    float*        hacc_g  = (float*)(w + 103680);   // 8*32 f32    = 1024 B
    unsigned int* counter = (unsigned int*)(w + 104704); // 4 B

    k_setup<<<dim3(BB + 2), dim3(256), 0, stream>>>(xcat, xfeat, embed, coefs,
                                                    xw, sw, ct, hacc_g, counter);
    k_gemm<<<dim3(TN, TM, BB), dim3(256), 0, stream>>>(xw, sw, ct, eq_bias,
                                                       hacc_g, counter,
                                                       out_w, out_b, out);
}

// Round 3
// 131.564 us; speedup vs baseline: 2.2374x; 2.2374x over previous
//
#include <hip/hip_runtime.h>
#include <cstdint>
#include <cstddef>

#define BB 8
#define NN 48
#define DD 33
#define XS 40            // xw/sw/ct row stride in floats (16B-aligned, zero-padded)
#define KP 128           // merged-K: [0,40)=xi*xj, [40,80)=xi*s, [80,120)=xj*s, 120=const
#define HH 32
#define MM (NN*NN)       // 2304 rows (i,j)
#define NC (NN*HH)       // 1536 cols (k,h)
#define TILE 96
#define TM (MM/TILE)     // 24 M-tiles
#define TN (NC/TILE)     // 16 N-tiles
#define NBLK (TM*TN)     // 384 blocks per batch
#define LDK 136          // LDS row stride f16 (+8 pad)

typedef __attribute__((ext_vector_type(8))) _Float16 f16x8;
typedef __attribute__((ext_vector_type(4))) float f32x4;

// ---- Kernel A: gather xw (padded), s = mean_i x, transpose coefs -> ct,
// ----           precompute const-column gk[b][k*32+h] -----------------------------
__global__ void k_setup(const int* __restrict__ xcat, const float* __restrict__ xfeat,
                        const float* __restrict__ embed, const float* __restrict__ coefs,
                        const float* __restrict__ eq_bias,
                        float* __restrict__ xw, float* __restrict__ sw,
                        float* __restrict__ ct, float* __restrict__ gk) {
    int b = blockIdx.x, t = threadIdx.x;
    __shared__ float sl[XS];
    if (b < BB) {
        for (int idx = t; idx < NN * XS; idx += 256) {
            int i = idx / XS, d = idx - i * XS;
            float v = 0.f;
            if (d < 32)       v = embed[xcat[b * NN + i] * 32 + d];
            else if (d == 32) v = xfeat[b * NN + i];
            xw[b * NN * XS + idx] = v;
        }
        __syncthreads();
        if (t < XS) {
            float a = 0.f;
            for (int i = 0; i < NN; ++i) a += xw[b * NN * XS + i * XS + t];
            float s = a * (1.0f / 48.0f);
            sw[b * XS + t] = s;
            sl[t] = s;
        }
        __syncthreads();
        // gk[b][k*32+h] = sum_d s^2 (c4[d,h]*x_k[d] + c7[d,h]*s[d]) + bias[h]
        for (int idx = t; idx < NC; idx += 256) {
            int k = idx >> 5, h = idx & 31;
            const float* xk = xw + (b * NN + k) * XS;
            float g = 0.f;
            for (int d = 0; d < DD; ++d) {
                float sd = sl[d];
                g += sd * sd * (coefs[(d * 8 + 4) * HH + h] * xk[d]
                              + coefs[(d * 8 + 7) * HH + h] * sd);
            }
            gk[b * NC + idx] = g + eq_bias[h];
        }
    } else {
        // ct[(q*32+h)*40 + d] = coefs[(d*8+q)*32 + h], zero-padded d>=33
        for (int idx = t; idx < 8 * HH * XS; idx += 256) {
            int qh = idx / XS, d = idx - qh * XS;
            int q = qh >> 5, h = qh & 31;
            ct[idx] = (d < DD) ? coefs[(d * 8 + q) * HH + h] : 0.f;
        }
    }
}

// ---- Kernel B: fused build(A,B) + 96x96 MFMA tile per block (3072 blocks);
// ----           relu + h-sum -> plain partial stores (NO global atomics) ---------
__global__ __launch_bounds__(256, 3) void k_gemm(
        const float* __restrict__ xw, const float* __restrict__ sw,
        const float* __restrict__ ct, const float* __restrict__ gk,
        float* __restrict__ partials) {
    __shared__ __align__(16) _Float16 As[TILE][LDK];
    __shared__ __align__(16) _Float16 Bs[TILE][LDK];
    __shared__ float hacc[HH];

    int t = threadIdx.x;
    int bx = blockIdx.x, by = blockIdx.y, b = blockIdx.z;
    int N0 = bx * TILE, M0 = by * TILE;
    const float* xb = xw + b * NN * XS;
    const float* sb = sw + b * XS;

    if (t < HH) hacc[t] = 0.f;

    // ---- build B tile (rows = (k,h)) and A tile (rows = (i,j)); no deps, 1 barrier ----
    for (int c = 0; c < 6; ++c) {
        int ch = c * 256 + t;
        int row = ch >> 4, d0 = (ch & 15) * 8;
        // B row
        {
            int n = N0 + row, k = n >> 5, h = n & 31;
            const float* xk = xb + k * XS;
            f16x8 v;
            if (d0 < 120) {
                int seg = (d0 >= 80) ? 2 : (d0 >= 40) ? 1 : 0;
                int d = d0 - seg * 40;
                const int QA[3] = {0, 2, 1}, QB[3] = {3, 6, 5};
                const float* ca = ct + (QA[seg] * HH + h) * XS + d;
                const float* cb = ct + (QB[seg] * HH + h) * XS + d;
                f32x4 ca0 = *(const f32x4*)(ca),     ca1 = *(const f32x4*)(ca + 4);
                f32x4 cb0 = *(const f32x4*)(cb),     cb1 = *(const f32x4*)(cb + 4);
                f32x4 xk0 = *(const f32x4*)(xk + d), xk1 = *(const f32x4*)(xk + d + 4);
                f32x4 sb0 = *(const f32x4*)(sb + d), sb1 = *(const f32x4*)(sb + d + 4);
                f32x4 r0 = ca0 * xk0 + cb0 * sb0;
                f32x4 r1 = ca1 * xk1 + cb1 * sb1;
                for (int e = 0; e < 4; ++e) { v[e] = (_Float16)r0[e]; v[4 + e] = (_Float16)r1[e]; }
            } else {
                v = (f16x8){0, 0, 0, 0, 0, 0, 0, 0};
                v[0] = (_Float16)gk[b * NC + N0 + row];
            }
            *(f16x8*)&Bs[row][d0] = v;
        }
        // A row
        {
            int grow = M0 + row;
            int i = grow / NN, j = grow - i * NN;
            f16x8 v;
            if (d0 < 120) {
                int seg = (d0 >= 80) ? 2 : (d0 >= 40) ? 1 : 0;
                int d = d0 - seg * 40;
                const float* p1 = (seg == 2) ? (xb + j * XS) : (xb + i * XS);
                const float* p2 = (seg == 0) ? (xb + j * XS) : sb;
                f32x4 a0 = *(const f32x4*)(p1 + d), a1 = *(const f32x4*)(p1 + d + 4);
                f32x4 b0 = *(const f32x4*)(p2 + d), b1 = *(const f32x4*)(p2 + d + 4);
                f32x4 r0 = a0 * b0, r1 = a1 * b1;
                for (int e = 0; e < 4; ++e) { v[e] = (_Float16)r0[e]; v[4 + e] = (_Float16)r1[e]; }
            } else {
                v = (f16x8){0, 0, 0, 0, 0, 0, 0, 0};
                v[0] = (_Float16)1.f;
            }
            *(f16x8*)&As[row][d0] = v;
        }
    }
    __syncthreads();

    int lane = t & 63, wave = t >> 6;
    int wm = (wave >> 1) * 48, wn = (wave & 1) * 48;
    int lrow = lane & 15, quad = lane >> 4;

    f32x4 acc[3][3];
#pragma unroll
    for (int m3 = 0; m3 < 3; ++m3)
#pragma unroll
        for (int nt = 0; nt < 3; ++nt)
            acc[m3][nt] = (f32x4){0.f, 0.f, 0.f, 0.f};

#pragma unroll
    for (int ks = 0; ks < 4; ++ks) {
        f16x8 af[3], bf[3];
#pragma unroll
        for (int m3 = 0; m3 < 3; ++m3)
            af[m3] = *(const f16x8*)&As[wm + m3 * 16 + lrow][ks * 32 + quad * 8];
#pragma unroll
        for (int nt = 0; nt < 3; ++nt)
            bf[nt] = *(const f16x8*)&Bs[wn + nt * 16 + lrow][ks * 32 + quad * 8];
#pragma unroll
        for (int m3 = 0; m3 < 3; ++m3)
#pragma unroll
            for (int nt = 0; nt < 3; ++nt)
                acc[m3][nt] = __builtin_amdgcn_mfma_f32_16x16x32_f16(af[m3], bf[nt], acc[m3][nt], 0, 0, 0);
    }

    // ---- relu + reduce: quads -> LDS -> plain partial store ----
    float fs[3] = {0.f, 0.f, 0.f};
#pragma unroll
    for (int m3 = 0; m3 < 3; ++m3)
#pragma unroll
        for (int nt = 0; nt < 3; ++nt)
#pragma unroll
            for (int r = 0; r < 4; ++r)
                fs[nt] += fmaxf(acc[m3][nt][r], 0.f);

#pragma unroll
    for (int nt = 0; nt < 3; ++nt) {
        float v = fs[nt];
        v += __shfl_xor(v, 16);
        v += __shfl_xor(v, 32);
        if (lane < 16) atomicAdd(&hacc[(wn + nt * 16 + lane) & 31], v);
    }
    __syncthreads();
    if (t < HH) {
        int blockLin = by * TN + bx;
        partials[((size_t)b * NBLK + blockLin) * HH + t] = hacc[t];
    }
}

// ---- Kernel C: per-batch reduce -> relu(mean) @ out_w + out_b ---------------------
__global__ void k_final(const float* __restrict__ partials, const float* __restrict__ out_w,
                        const float* __restrict__ out_b, float* __restrict__ out) {
    __shared__ float red[256];
    int b = blockIdx.x, t = threadIdx.x;
    int h = t & 31, g = t >> 5;
    float a = 0.f;
    for (int p = g; p < NBLK; p += 8) a += partials[((size_t)b * NBLK + p) * HH + h];
    red[t] = a;
    __syncthreads();
    if (t < HH) {
        float tot = 0.f;
        for (int gg = 0; gg < 8; ++gg) tot += red[gg * 32 + t];
        float m = tot * (1.0f / 110592.0f);
        red[t] = fmaxf(m, 0.f) * out_w[t];
    }
    __syncthreads();
    if (t == 0) {
        float o = 0.f;
        for (int h2 = 0; h2 < HH; ++h2) o += red[h2];
        out[b] = o + out_b[0];
    }
}

extern "C" void kernel_launch(void* const* d_in, const int* in_sizes, int n_in,
                              void* d_out, int out_size, void* d_ws, size_t ws_size,
                              hipStream_t stream) {
    (void)in_sizes; (void)n_in; (void)out_size; (void)ws_size;
    const int*   xcat    = (const int*)d_in[0];
    const float* xfeat   = (const float*)d_in[1];
    const float* embed   = (const float*)d_in[2];
    const float* coefs   = (const float*)d_in[3];
    const float* eq_bias = (const float*)d_in[4];
    const float* out_w   = (const float*)d_in[5];
    const float* out_b   = (const float*)d_in[6];
    float* out = (float*)d_out;

    // Workspace layout (16B-aligned), total ~546 KB
    char* w = (char*)d_ws;
    float* xw       = (float*)(w + 0);        // 8*48*40 f32 = 61440 B
    float* sw       = (float*)(w + 61440);    // 8*40 f32    = 1280 B
    float* ct       = (float*)(w + 62720);    // 8*32*40 f32 = 40960 B
    float* gk       = (float*)(w + 103680);   // 8*1536 f32  = 49152 B
    float* partials = (float*)(w + 152832);   // 8*384*32 f32 = 393216 B

    k_setup<<<dim3(BB + 1), dim3(256), 0, stream>>>(xcat, xfeat, embed, coefs, eq_bias,
                                                    xw, sw, ct, gk);
    k_gemm<<<dim3(TN, TM, BB), dim3(256), 0, stream>>>(xw, sw, ct, gk, partials);
    k_final<<<dim3(BB), dim3(256), 0, stream>>>(partials, out_w, out_b, out);
}

// Round 4
// 108.677 us; speedup vs baseline: 2.7086x; 1.2106x over previous
//
#include <hip/hip_runtime.h>
#include <cstdint>
#include <cstddef>

#define BB 8
#define NN 48
#define DD 33
#define XS 40            // xw/sw/ct row stride in floats (16B-aligned, zero-padded)
#define KP 128           // merged-K: [0,40)=xi*xj, [40,80)=xi*s, [80,120)=xj*s, 120=const
#define HH 32
#define MM (NN*NN)       // 2304 rows (i,j)
#define NC (NN*HH)       // 1536 cols (k,h)
#define TILE 96
#define TM (MM/TILE)     // 24 M-tiles
#define TN (NC/TILE)     // 16 N-tiles
#define NBLK (TM*TN)     // 384 blocks per batch
#define LDK 136          // LDS row stride f16 (+8 pad)
#define ABLK (BB*MM/16)  // 1152 build blocks for A (each thread = one 16B chunk)
#define BBLK (BB*NC/16)  // 768 build blocks for B

typedef __attribute__((ext_vector_type(8))) _Float16 f16x8;
typedef __attribute__((ext_vector_type(4))) float f32x4;

// ---- Kernel A: gather xw (padded), s = mean_i x, transpose coefs -> ct,
// ----           precompute const-column gk[b][k*32+h] -----------------------------
__global__ void k_setup(const int* __restrict__ xcat, const float* __restrict__ xfeat,
                        const float* __restrict__ embed, const float* __restrict__ coefs,
                        const float* __restrict__ eq_bias,
                        float* __restrict__ xw, float* __restrict__ sw,
                        float* __restrict__ ct, float* __restrict__ gk) {
    int b = blockIdx.x, t = threadIdx.x;
    __shared__ float sl[XS];
    if (b < BB) {
        for (int idx = t; idx < NN * XS; idx += 256) {
            int i = idx / XS, d = idx - i * XS;
            float v = 0.f;
            if (d < 32)       v = embed[xcat[b * NN + i] * 32 + d];
            else if (d == 32) v = xfeat[b * NN + i];
            xw[b * NN * XS + idx] = v;
        }
        __syncthreads();
        if (t < XS) {
            float a = 0.f;
            for (int i = 0; i < NN; ++i) a += xw[b * NN * XS + i * XS + t];
            float s = a * (1.0f / 48.0f);
            sw[b * XS + t] = s;
            sl[t] = s;
        }
        __syncthreads();
        // gk[b][k*32+h] = sum_d s^2 (c4[d,h]*x_k[d] + c7[d,h]*s[d]) + bias[h]
        for (int idx = t; idx < NC; idx += 256) {
            int k = idx >> 5, h = idx & 31;
            const float* xk = xw + (b * NN + k) * XS;
            float g = 0.f;
            for (int d = 0; d < DD; ++d) {
                float sd = sl[d];
                g += sd * sd * (coefs[(d * 8 + 4) * HH + h] * xk[d]
                              + coefs[(d * 8 + 7) * HH + h] * sd);
            }
            gk[b * NC + idx] = g + eq_bias[h];
        }
    } else {
        // ct[(q*32+h)*40 + d] = coefs[(d*8+q)*32 + h], zero-padded d>=33
        for (int idx = t; idx < 8 * HH * XS; idx += 256) {
            int qh = idx / XS, d = idx - qh * XS;
            int q = qh >> 5, h = qh & 31;
            ct[idx] = (d < DD) ? coefs[(d * 8 + q) * HH + h] : 0.f;
        }
    }
}

// ---- Kernel B: build Aw[(b,i,j),128] and Bw[(b,k,h),128] f16, each row ONCE ------
__global__ __launch_bounds__(256) void k_build(
        const float* __restrict__ xw, const float* __restrict__ sw,
        const float* __restrict__ ct, const float* __restrict__ gk,
        _Float16* __restrict__ Aw, _Float16* __restrict__ Bw) {
    int t = threadIdx.x, blk = blockIdx.x;
    if (blk < ABLK) {
        int g = blk * 256 + t;                    // chunk id over A
        int row = g >> 4, d0 = (g & 15) * 8;
        int b = row / MM, grow = row - b * MM;
        int i = grow / NN, j = grow - i * NN;
        const float* xb = xw + b * NN * XS;
        const float* sb = sw + b * XS;
        f16x8 v;
        if (d0 < 120) {
            int seg = (d0 >= 80) ? 2 : (d0 >= 40) ? 1 : 0;
            int d = d0 - seg * 40;
            const float* p1 = (seg == 2) ? (xb + j * XS) : (xb + i * XS);
            const float* p2 = (seg == 0) ? (xb + j * XS) : sb;
            f32x4 a0 = *(const f32x4*)(p1 + d), a1 = *(const f32x4*)(p1 + d + 4);
            f32x4 b0 = *(const f32x4*)(p2 + d), b1 = *(const f32x4*)(p2 + d + 4);
            f32x4 r0 = a0 * b0, r1 = a1 * b1;
            for (int e = 0; e < 4; ++e) { v[e] = (_Float16)r0[e]; v[4 + e] = (_Float16)r1[e]; }
        } else {
            v = (f16x8){0, 0, 0, 0, 0, 0, 0, 0};
            v[0] = (_Float16)1.f;
        }
        *(f16x8*)&Aw[(size_t)row * KP + d0] = v;
    } else {
        int g = (blk - ABLK) * 256 + t;           // chunk id over B
        int row = g >> 4, d0 = (g & 15) * 8;
        int b = row / NC, n = row - b * NC;
        int k = n >> 5, h = n & 31;
        const float* xk = xw + (b * NN + k) * XS;
        const float* sb = sw + b * XS;
        f16x8 v;
        if (d0 < 120) {
            int seg = (d0 >= 80) ? 2 : (d0 >= 40) ? 1 : 0;
            int d = d0 - seg * 40;
            const int QA[3] = {0, 2, 1}, QB[3] = {3, 6, 5};
            const float* ca = ct + (QA[seg] * HH + h) * XS + d;
            const float* cb = ct + (QB[seg] * HH + h) * XS + d;
            f32x4 ca0 = *(const f32x4*)(ca),     ca1 = *(const f32x4*)(ca + 4);
            f32x4 cb0 = *(const f32x4*)(cb),     cb1 = *(const f32x4*)(cb + 4);
            f32x4 xk0 = *(const f32x4*)(xk + d), xk1 = *(const f32x4*)(xk + d + 4);
            f32x4 sb0 = *(const f32x4*)(sb + d), sb1 = *(const f32x4*)(sb + d + 4);
            f32x4 r0 = ca0 * xk0 + cb0 * sb0;
            f32x4 r1 = ca1 * xk1 + cb1 * sb1;
            for (int e = 0; e < 4; ++e) { v[e] = (_Float16)r0[e]; v[4 + e] = (_Float16)r1[e]; }
        } else {
            v = (f16x8){0, 0, 0, 0, 0, 0, 0, 0};
            v[0] = (_Float16)gk[b * NC + n];
        }
        *(f16x8*)&Bw[(size_t)row * KP + d0] = v;
    }
}

// ---- Kernel C: pure 96x96x128 MFMA GEMM per block (3072 blocks);
// ----           relu + h-sum -> plain partial stores ------------------------------
__global__ __launch_bounds__(256, 3) void k_gemm(
        const _Float16* __restrict__ Aw, const _Float16* __restrict__ Bw,
        float* __restrict__ partials) {
    __shared__ __align__(16) _Float16 As[TILE][LDK];
    __shared__ __align__(16) _Float16 Bs[TILE][LDK];
    __shared__ float hacc[HH];

    int t = threadIdx.x;
    int bx = blockIdx.x, by = blockIdx.y, b = blockIdx.z;
    int N0 = bx * TILE, M0 = by * TILE;
    const _Float16* Ag = Aw + ((size_t)(b * MM + M0)) * KP;
    const _Float16* Bg = Bw + ((size_t)(b * NC + N0)) * KP;

    if (t < HH) hacc[t] = 0.f;

    // ---- stage both tiles: 12 x {global 16B load -> LDS 16B write} per thread ----
#pragma unroll
    for (int c = 0; c < 6; ++c) {
        int ch = c * 256 + t;
        int row = ch >> 4, d0 = (ch & 15) * 8;
        f16x8 va = *(const f16x8*)(Ag + row * KP + d0);
        f16x8 vb = *(const f16x8*)(Bg + row * KP + d0);
        *(f16x8*)&As[row][d0] = va;
        *(f16x8*)&Bs[row][d0] = vb;
    }
    __syncthreads();

    int lane = t & 63, wave = t >> 6;
    int wm = (wave >> 1) * 48, wn = (wave & 1) * 48;
    int lrow = lane & 15, quad = lane >> 4;

    f32x4 acc[3][3];
#pragma unroll
    for (int m3 = 0; m3 < 3; ++m3)
#pragma unroll
        for (int nt = 0; nt < 3; ++nt)
            acc[m3][nt] = (f32x4){0.f, 0.f, 0.f, 0.f};

#pragma unroll
    for (int ks = 0; ks < 4; ++ks) {
        f16x8 af[3], bf[3];
#pragma unroll
        for (int m3 = 0; m3 < 3; ++m3)
            af[m3] = *(const f16x8*)&As[wm + m3 * 16 + lrow][ks * 32 + quad * 8];
#pragma unroll
        for (int nt = 0; nt < 3; ++nt)
            bf[nt] = *(const f16x8*)&Bs[wn + nt * 16 + lrow][ks * 32 + quad * 8];
#pragma unroll
        for (int m3 = 0; m3 < 3; ++m3)
#pragma unroll
            for (int nt = 0; nt < 3; ++nt)
                acc[m3][nt] = __builtin_amdgcn_mfma_f32_16x16x32_f16(af[m3], bf[nt], acc[m3][nt], 0, 0, 0);
    }

    // ---- relu + reduce: quads -> LDS -> plain partial store ----
    float fs[3] = {0.f, 0.f, 0.f};
#pragma unroll
    for (int m3 = 0; m3 < 3; ++m3)
#pragma unroll
        for (int nt = 0; nt < 3; ++nt)
#pragma unroll
            for (int r = 0; r < 4; ++r)
                fs[nt] += fmaxf(acc[m3][nt][r], 0.f);

#pragma unroll
    for (int nt = 0; nt < 3; ++nt) {
        float v = fs[nt];
        v += __shfl_xor(v, 16);
        v += __shfl_xor(v, 32);
        if (lane < 16) atomicAdd(&hacc[(wn + nt * 16 + lane) & 31], v);
    }
    __syncthreads();
    if (t < HH) {
        int blockLin = by * TN + bx;
        partials[((size_t)b * NBLK + blockLin) * HH + t] = hacc[t];
    }
}

// ---- Kernel D: per-batch reduce -> relu(mean) @ out_w + out_b ---------------------
__global__ void k_final(const float* __restrict__ partials, const float* __restrict__ out_w,
                        const float* __restrict__ out_b, float* __restrict__ out) {
    __shared__ float red[256];
    int b = blockIdx.x, t = threadIdx.x;
    int h = t & 31, g = t >> 5;
    float a = 0.f;
    for (int p = g; p < NBLK; p += 8) a += partials[((size_t)b * NBLK + p) * HH + h];
    red[t] = a;
    __syncthreads();
    if (t < HH) {
        float tot = 0.f;
        for (int gg = 0; gg < 8; ++gg) tot += red[gg * 32 + t];
        float m = tot * (1.0f / 110592.0f);
        red[t] = fmaxf(m, 0.f) * out_w[t];
    }
    __syncthreads();
    if (t == 0) {
        float o = 0.f;
        for (int h2 = 0; h2 < HH; ++h2) o += red[h2];
        out[b] = o + out_b[0];
    }
}

extern "C" void kernel_launch(void* const* d_in, const int* in_sizes, int n_in,
                              void* d_out, int out_size, void* d_ws, size_t ws_size,
                              hipStream_t stream) {
    (void)in_sizes; (void)n_in; (void)out_size; (void)ws_size;
    const int*   xcat    = (const int*)d_in[0];
    const float* xfeat   = (const float*)d_in[1];
    const float* embed   = (const float*)d_in[2];
    const float* coefs   = (const float*)d_in[3];
    const float* eq_bias = (const float*)d_in[4];
    const float* out_w   = (const float*)d_in[5];
    const float* out_b   = (const float*)d_in[6];
    float* out = (float*)d_out;

    // Workspace layout (16B-aligned), total ~8.4 MB
    char* w = (char*)d_ws;
    float*    xw       = (float*)(w + 0);        // 8*48*40 f32   = 61440 B
    float*    sw       = (float*)(w + 61440);    // 8*40 f32      = 1280 B
    float*    ct       = (float*)(w + 62720);    // 8*32*40 f32   = 40960 B
    float*    gk       = (float*)(w + 103680);   // 8*1536 f32    = 49152 B
    _Float16* Aw       = (_Float16*)(w + 152832);// 8*2304*128 f16 = 4718592 B
    _Float16* Bw       = (_Float16*)(w + 4871424);// 8*1536*128 f16 = 3145728 B
    float*    partials = (float*)(w + 8017152);  // 8*384*32 f32  = 393216 B

    k_setup<<<dim3(BB + 1), dim3(256), 0, stream>>>(xcat, xfeat, embed, coefs, eq_bias,
                                                    xw, sw, ct, gk);
    k_build<<<dim3(ABLK + BBLK), dim3(256), 0, stream>>>(xw, sw, ct, gk, Aw, Bw);
    k_gemm<<<dim3(TN, TM, BB), dim3(256), 0, stream>>>(Aw, Bw, partials);
    k_final<<<dim3(BB), dim3(256), 0, stream>>>(partials, out_w, out_b, out);
}